// Round 14
// baseline (1108.971 us; speedup 1.0000x reference)
//
#include <hip/hip_runtime.h>
#include <type_traits>

// ---------------- problem constants ----------------
static const long BATCH = 131072;
static const int ROWS = 32;                  // rows per block (final/fallback)
static const int NBLOCKS = 4096;             // fallback/final grid
static const int GBLOCKS = 2048;             // gemm_mfma grid (64 rows each)

using f64x4 = __attribute__((ext_vector_type(4))) double;

// ---------------- threefry2x32 (JAX partitionable, key = (0, 42)) ----------
__device__ __forceinline__ unsigned rotl32(unsigned x, int d) {
  return (x << d) | (x >> (32 - d));
}

struct U2 { unsigned a, b; };

__device__ __forceinline__ U2 threefry(unsigned x0, unsigned x1) {
  const unsigned ks0 = 0u, ks1 = 42u, ks2 = 0u ^ 42u ^ 0x1BD11BDAu;
  x0 += ks0; x1 += ks1;
#define TF_R4(A,B,C,D) \
  x0 += x1; x1 = rotl32(x1, A); x1 ^= x0; \
  x0 += x1; x1 = rotl32(x1, B); x1 ^= x0; \
  x0 += x1; x1 = rotl32(x1, C); x1 ^= x0; \
  x0 += x1; x1 = rotl32(x1, D); x1 ^= x0;
  TF_R4(13,15,26,6)  x0 += ks1; x1 += ks2 + 1u;
  TF_R4(17,29,16,24) x0 += ks2; x1 += ks0 + 2u;
  TF_R4(13,15,26,6)  x0 += ks0; x1 += ks1 + 3u;
  TF_R4(17,29,16,24) x0 += ks1; x1 += ks2 + 4u;
  TF_R4(13,15,26,6)  x0 += ks2; x1 += ks0 + 5u;
#undef TF_R4
  U2 r; r.a = x0; r.b = x1; return r;
}

// partitionable 32-bit draw: bits1 ^ bits2  (VERIFIED passing, round 4)
__device__ __forceinline__ float jax_uniform(unsigned idx) {
  U2 r = threefry(0u, idx);
  unsigned bits = r.a ^ r.b;
  unsigned fb = (bits >> 9) | 0x3f800000u;
  return __uint_as_float(fb) - 1.0f;
}

// ============ f64-MFMA D-fragment layout probe (VERIFIED round 7) ==========
__global__ __launch_bounds__(64) void probe_layout(unsigned* __restrict__ maps) {
  __shared__ double X1[16][5], X2[16][5], W1s[4][17], W2s[4][17];
  const int l = threadIdx.x;
  const int lr = l & 15, lk = l >> 4;
  {
    int i = l >> 2, k = l & 3;
    X1[i][k] = (k == 0) ? (double)i : 0.0;   // D1[i][j] = i
    X2[i][k] = (k == 0) ? 1.0 : 0.0;         // D2[i][j] = j
    W1s[k][i] = (k == 0) ? 1.0 : 0.0;
    W2s[k][i] = (k == 0) ? (double)i : 0.0;
  }
  __syncthreads();
  f64x4 a1 = {0.0, 0.0, 0.0, 0.0}, a2 = {0.0, 0.0, 0.0, 0.0};
  a1 = __builtin_amdgcn_mfma_f64_16x16x4f64(X1[lr][lk], W1s[lk][lr], a1, 0, 0, 0);
  a2 = __builtin_amdgcn_mfma_f64_16x16x4f64(X2[lr][lk], W2s[lk][lr], a2, 0, 0, 0);
  unsigned m = 0;
  #pragma unroll
  for (int r = 0; r < 4; ++r) {
    int row = (int)(a1[r] + 0.5);
    int col = (int)(a2[r] + 0.5);
    m |= (unsigned)(((row & 15) << 4) | (col & 15)) << (8 * r);
  }
  maps[l] = m;
}

// ====== FAST PATH: f64-MFMA GEMM (R9 structure + distance-2 W prefetch) ====
// h[B][N] = act(in[B][M]) @ W[N][M]^T + b; col stats partials transposed.
// A direct-to-reg (distance 1); W double-buffered in LDS with REGISTER
// prefetch DISTANCE 2: loads for chunk ch+2 issued at iter ch, consumed by
// writeW at iter ch+1 -> ~2 iterations (>500cy) in flight, covering L2/HBM
// latency that was exposed at distance 1 (the ~30% MFMA-idle in R9..R13).
template<int M, int N, int MODE>
__global__ __launch_bounds__(256, 3) void gemm_mfma(
    const void* __restrict__ inv, const float* __restrict__ W,
    const float* __restrict__ bias,
    const double* __restrict__ bna, const double* __restrict__ bnc,
    const unsigned* __restrict__ maps_g,
    double* __restrict__ hout, double* __restrict__ partials)
{
  constexpr int BK = 16;
  constexpr int NT = (N + 15) / 16;
  constexpr int NPAD = NT * 16;
  constexpr int WSTR = NPAD + 2;              // lk-groups 8 banks apart
  constexpr int NCH = (M + BK - 1) / BK;
  constexpr int NW = BK * NPAD;
  constexpr int WLD = (NW + 255) / 256;
  constexpr int SMK = (MODE == 1) ? (NCH * BK) : 1;

  struct SMM { float ws[2][BK][WSTR]; double bn[2][SMK]; };
  union SMEM { SMM m; double tt[4][16][17]; };
  __shared__ SMEM sm;

  const int tid = threadIdx.x;
  const int w = tid >> 6, l = tid & 63;
  const int lr = l & 15, lk = l >> 4;
  const long i0 = (long)blockIdx.x * 64;
  const int wrow = w * 16;
  const unsigned um = maps_g[l];
  const long arow = i0 + wrow + lr;           // this lane's A row

  if constexpr (MODE == 1) {
    for (int k = tid; k < SMK; k += 256) {
      sm.m.bn[0][k] = (k < M) ? bna[k] : 0.0;
      sm.m.bn[1][k] = (k < M) ? bnc[k] : 0.0;
    }
  }

  float wregA[WLD], wregB[WLD];               // distance-2 W prefetch sets
  float a4f[4], a4fn[4];
  double a4d[4], a4dn[4];

  auto loadW = [&](int k0, float* dst) {
    #pragma unroll
    for (int p = 0; p < WLD; ++p) {
      int idx = tid + p * 256;
      float v = 0.0f;
      if (idx < NW) {
        int j = idx >> 4, kk = idx & 15;
        int k = k0 + kk;
        if (j < N && k < M) v = W[(long)j * M + k];
      }
      dst[p] = v;
    }
  };
  auto writeW = [&](int buf, const float* src) {
    #pragma unroll
    for (int p = 0; p < WLD; ++p) {
      int idx = tid + p * 256;
      if (idx < NW) {
        int j = idx >> 4, kk = idx & 15;
        sm.m.ws[buf][kk][j] = src[p];
      }
    }
  };
  auto loadA = [&](int k0, bool nxt) {
    int kb = k0 + lk * 4;
    if constexpr (MODE == 0) {
      float* dst = nxt ? a4fn : a4f;
      float4 v = *(const float4*)((const float*)inv + arow * (long)M + kb);
      dst[0] = v.x; dst[1] = v.y; dst[2] = v.z; dst[3] = v.w;
    } else {
      double* dst = nxt ? a4dn : a4d;
      if (kb + 4 <= M) {
        const double* ap = (const double*)inv + arow * (long)M + kb;
        double2 lo = *(const double2*)ap;
        double2 hi = *(const double2*)(ap + 2);
        dst[0] = lo.x; dst[1] = lo.y; dst[2] = hi.x; dst[3] = hi.y;
      } else {
        #pragma unroll
        for (int e = 0; e < 4; ++e)
          dst[e] = (kb + e < M) ? ((const double*)inv)[arow * (long)M + kb + e] : 0.0;
      }
    }
  };

  f64x4 acc[NT];
  #pragma unroll
  for (int t = 0; t < NT; ++t) acc[t] = (f64x4){0.0, 0.0, 0.0, 0.0};

  // ---- prologue: chunks 0 and 1 in flight ----
  loadA(0, false);
  loadW(0, wregA);                            // chunk 0 -> set A (parity 0)
  if (1 < NCH) loadW(BK, wregB);              // chunk 1 -> set B (parity 1)
  writeW(0, wregA);
  __syncthreads();
  int cur = 0;
  for (int ch = 0; ch < NCH; ++ch) {
    const int k0 = ch * BK;
    // issue chunk ch+2 into the set freed last iteration (parity ch&1)
    if (ch + 2 < NCH) {
      if ((ch & 1) == 0) loadW(k0 + 2 * BK, wregA);
      else               loadW(k0 + 2 * BK, wregB);
    }
    if (ch + 1 < NCH) loadA(k0 + BK, true);
    #pragma unroll
    for (int ks = 0; ks < 4; ++ks) {
      double aA;
      if constexpr (MODE == 0) {
        aA = (double)a4f[ks];
      } else {
        int k = k0 + lk * 4 + ks;
        double v = a4d[ks] * sm.m.bn[0][k] + sm.m.bn[1][k];
        aA = v > 0.0 ? v : 0.0;
      }
      #pragma unroll
      for (int t = 0; t < NT; ++t) {
        double bB = (double)sm.m.ws[cur][lk * 4 + ks][t * 16 + lr];
        acc[t] = __builtin_amdgcn_mfma_f64_16x16x4f64(aA, bB, acc[t], 0, 0, 0);
      }
    }
    // write chunk ch+1 (loaded at iter ch-1 -> ~2 iterations in flight)
    if (ch + 1 < NCH) {
      if (((ch + 1) & 1) == 0) writeW(cur ^ 1, wregA);
      else                     writeW(cur ^ 1, wregB);
    }
    __syncthreads();
    if (ch + 1 < NCH) {
      if constexpr (MODE == 0) {
        #pragma unroll
        for (int e = 0; e < 4; ++e) a4f[e] = a4fn[e];
      } else {
        #pragma unroll
        for (int e = 0; e < 4; ++e) a4d[e] = a4dn[e];
      }
      cur ^= 1;
    }
  }

  // ---- epilogue: map-driven LDS transpose (tt unions staging), store+stats --
  const int blk = blockIdx.x;
  for (int t = 0; t < NT; ++t) {
    __syncthreads();
    #pragma unroll
    for (int r = 0; r < 4; ++r) {
      unsigned b = (um >> (8 * r)) & 0xffu;
      sm.tt[w][b >> 4][b & 15] = acc[t][r];
    }
    __syncthreads();
    for (int idx = tid; idx < 1024; idx += 256) {
      int rb = idx >> 4, j16 = idx & 15;
      int j = t * 16 + j16;
      if (j < N) {
        double h = sm.tt[rb >> 4][rb & 15][j16] + (double)bias[j];
        hout[(i0 + rb) * (long)N + j] = h;
      }
    }
    if (tid < 64) {
      int j16 = tid >> 2, part = tid & 3;
      int j = t * 16 + j16;
      double s = 0.0, q = 0.0;
      if (j < N) {
        double bj = (double)bias[j];
        #pragma unroll
        for (int rr = 0; rr < 16; ++rr) {
          int rb = part * 16 + rr;
          double h = sm.tt[rb >> 4][rb & 15][j16] + bj;
          s += h; q += h * h;
        }
      }
      s += __shfl_xor(s, 1); s += __shfl_xor(s, 2);
      q += __shfl_xor(q, 1); q += __shfl_xor(q, 2);
      if (part == 0 && j < N) {
        partials[(long)j * GBLOCKS + blk] = s;
        partials[(long)(N + j) * GBLOCKS + blk] = q;
      }
    }
  }
}

// final: BN+ReLU(h4) -> Linear(50->64) -> sigmoid -> sample -> logsum
__global__ __launch_bounds__(256) void final_store(
    const double* __restrict__ h4,
    const double* __restrict__ bna, const double* __restrict__ bnc,
    const float* __restrict__ W5, const float* __restrict__ b5,
    float* __restrict__ out0, float* __restrict__ out1)
{
  __shared__ double A5[ROWS][51];
  __shared__ double W5S[50][65];
  __shared__ double T[ROWS][65];
  const int tid = threadIdx.x;
  const int c = tid & 63, g = tid >> 6;
  const long i0 = (long)blockIdx.x * ROWS;

  for (int idx = tid; idx < ROWS * 50; idx += 256) {
    int r = idx / 50, k = idx % 50;
    double v = h4[(i0 + r) * 50 + k] * bna[k] + bnc[k];
    A5[r][k] = v > 0.0 ? v : 0.0;
  }
  for (int idx = tid; idx < 64 * 50; idx += 256) {
    int j = idx / 50, k = idx % 50;
    W5S[k][j] = (double)W5[j * 50 + k];
  }
  __syncthreads();

  double acc[8];
  #pragma unroll
  for (int rr = 0; rr < 8; ++rr) acc[rr] = 0.0;
  for (int k = 0; k < 50; ++k) {
    double w = W5S[k][c];
    #pragma unroll
    for (int rr = 0; rr < 8; ++rr) acc[rr] += A5[g * 8 + rr][k] * w;
  }
  double bj = (double)b5[c];
  #pragma unroll
  for (int rr = 0; rr < 8; ++rr) {
    int r = g * 8 + rr;
    double h = acc[rr] + bj;
    double p = 1.0 / (1.0 + exp(-h));
    float uf = jax_uniform((unsigned)((i0 + r) * 64 + c));
    bool ch = ((double)uf < 1.0 - p);
    out0[(i0 + r) * 64 + c] = ch ? 0.0f : 1.0f;
    T[r][c] = log(ch ? (1.0 - p) : p);
  }
  __syncthreads();
  for (int r = tid; r < ROWS; r += 256) {
    double s = 0.0;
    for (int j = 0; j < 64; ++j) s += T[r][j];
    out1[i0 + r] = (float)s;
  }
}

// ======================= FALLBACK: recompute chain (verified) ==============
template<int M, int N>
__device__ __forceinline__ void step_gemm(const double* IN, const float* __restrict__ W,
                                          int tid, double* acc) {
  if (tid < N) {
    #pragma unroll
    for (int r = 0; r < 32; ++r) acc[r] = 0.0;
    for (int k = 0; k < M; ++k) {
      double wv = (double)W[tid * M + k];
      #pragma unroll
      for (int r = 0; r < 32; ++r) acc[r] += IN[r * M + k] * wv;
    }
  }
}

template<int N>
__device__ __forceinline__ void step_write(double* OUT, const double* acc,
                                           const float* __restrict__ b, int tid) {
  if (tid < N) {
    double bj = (double)b[tid];
    #pragma unroll
    for (int r = 0; r < 32; ++r) OUT[r * N + tid] = acc[r] + bj;
  }
}

// transposed partials layout: partials[j*NBLOCKS + blk]
template<int N>
__device__ __forceinline__ void step_stats(const double* acc, const float* __restrict__ b,
                                           double* partials, int blk, int tid) {
  if (tid < N) {
    double bj = (double)b[tid], s = 0.0, q = 0.0;
    #pragma unroll
    for (int r = 0; r < 32; ++r) { double h = acc[r] + bj; s += h; q += h * h; }
    partials[(long)tid * NBLOCKS + blk] = s;
    partials[(long)(N + tid) * NBLOCKS + blk] = q;
  }
}

template<int N>
__device__ __forceinline__ void apply_bn(double* BUF, const double* __restrict__ a,
                                         const double* __restrict__ c, int tid) {
  for (int idx = tid; idx < 32 * N; idx += 256) {
    int col = idx % N;
    double v = BUF[idx] * a[col] + c[col];
    BUF[idx] = v > 0.0 ? v : 0.0;
  }
}

template<int PL>
__global__ __launch_bounds__(256) void chain_pass(
    const float* __restrict__ ev,
    const float* __restrict__ W0, const float* __restrict__ b0,
    const float* __restrict__ W1, const float* __restrict__ b1,
    const float* __restrict__ W2, const float* __restrict__ b2,
    const float* __restrict__ W3, const float* __restrict__ b3,
    const float* __restrict__ W4, const float* __restrict__ b4,
    const float* __restrict__ W5, const float* __restrict__ b5,
    const double* __restrict__ bn_a, const double* __restrict__ bn_c,
    double* __restrict__ partials,
    float* __restrict__ out0, float* __restrict__ out1)
{
  __shared__ double SA[32 * 130];
  __shared__ double SB[32 * 110];
  const int tid = threadIdx.x;
  const int blk = blockIdx.x;
  const long i0 = (long)blk * 32;
  double acc[32];

  {
    float* evf = (float*)SA;
    if (tid < 130) {
      #pragma unroll
      for (int r = 0; r < 32; ++r) acc[r] = 0.0;
    }
    for (int c = 0; c < 4; ++c) {
      __syncthreads();
      for (int idx = tid; idx < 32 * 256; idx += 256) {
        int r = idx >> 8, kk = idx & 255;
        evf[idx] = ev[(i0 + r) * 1024 + c * 256 + kk];
      }
      __syncthreads();
      if (tid < 130) {
        for (int kk = 0; kk < 256; ++kk) {
          double wv = (double)W0[tid * 1024 + c * 256 + kk];
          #pragma unroll
          for (int r = 0; r < 32; ++r) acc[r] += (double)evf[r * 256 + kk] * wv;
        }
      }
    }
    __syncthreads();
    if constexpr (PL == 0) { step_stats<130>(acc, b0, partials, blk, tid); return; }
    step_write<130>(SA, acc, b0, tid);
    __syncthreads();
    apply_bn<130>(SA, bn_a + 0, bn_c + 0, tid);
    __syncthreads();
  }
  if constexpr (PL >= 1) {
    step_gemm<130, 110>(SA, W1, tid, acc);
    if constexpr (PL == 1) { step_stats<110>(acc, b1, partials, blk, tid); return; }
    __syncthreads();
    step_write<110>(SB, acc, b1, tid);
    __syncthreads();
    apply_bn<110>(SB, bn_a + 130, bn_c + 130, tid);
    __syncthreads();
  }
  if constexpr (PL >= 2) {
    step_gemm<110, 90>(SB, W2, tid, acc);
    if constexpr (PL == 2) { step_stats<90>(acc, b2, partials, blk, tid); return; }
    __syncthreads();
    step_write<90>(SA, acc, b2, tid);
    __syncthreads();
    apply_bn<90>(SA, bn_a + 240, bn_c + 240, tid);
    __syncthreads();
  }
  if constexpr (PL >= 3) {
    step_gemm<90, 70>(SA, W3, tid, acc);
    if constexpr (PL == 3) { step_stats<70>(acc, b3, partials, blk, tid); return; }
    __syncthreads();
    step_write<70>(SB, acc, b3, tid);
    __syncthreads();
    apply_bn<70>(SB, bn_a + 330, bn_c + 330, tid);
    __syncthreads();
  }
  if constexpr (PL >= 4) {
    step_gemm<70, 50>(SB, W4, tid, acc);
    if constexpr (PL == 4) { step_stats<50>(acc, b4, partials, blk, tid); return; }
    __syncthreads();
    step_write<50>(SA, acc, b4, tid);
    __syncthreads();
    apply_bn<50>(SA, bn_a + 400, bn_c + 400, tid);
    __syncthreads();
  }
  if constexpr (PL == 5) {
    if (tid < 64) {
      #pragma unroll
      for (int r = 0; r < 32; ++r) acc[r] = 0.0;
      for (int k = 0; k < 50; ++k) {
        double wv = (double)W5[tid * 50 + k];
        #pragma unroll
        for (int r = 0; r < 32; ++r) acc[r] += SA[r * 50 + k] * wv;
      }
      double bj = (double)b5[tid];
      #pragma unroll
      for (int r = 0; r < 32; ++r) {
        double h = acc[r] + bj;
        double p = 1.0 / (1.0 + exp(-h));
        float uf = jax_uniform((unsigned)((i0 + r) * 64 + tid));
        bool ch = ((double)uf < 1.0 - p);
        out0[(i0 + r) * 64 + tid] = ch ? 0.0f : 1.0f;
        double d = ch ? (1.0 - p) : p;
        SB[r * 64 + tid] = log(d);
      }
    }
    __syncthreads();
    if (tid < 32) {
      double s = 0.0;
      for (int j = 0; j < 64; ++j) s += SB[tid * 64 + j];
      out1[i0 + tid] = (float)s;
    }
  }
}

// ------- BN stats finalize: transposed partials -> a, c (coalesced) --------
template<int N>
__global__ __launch_bounds__(256) void bn_finalize2(
    const double* __restrict__ partials, int nblocks,
    const float* __restrict__ g, const float* __restrict__ be,
    double* __restrict__ a, double* __restrict__ c)
{
  const int j = blockIdx.x;
  const int tid = threadIdx.x;
  double s = 0.0, q = 0.0;
  for (int b = tid; b < nblocks; b += 256) {
    s += partials[(long)j * nblocks + b];
    q += partials[(long)(N + j) * nblocks + b];
  }
  __shared__ double ls[256], lq[256];
  ls[tid] = s; lq[tid] = q;
  __syncthreads();
  for (int off = 128; off > 0; off >>= 1) {
    if (tid < off) { ls[tid] += ls[tid + off]; lq[tid] += lq[tid + off]; }
    __syncthreads();
  }
  if (tid == 0) {
    double mu  = ls[0] * (1.0 / 131072.0);
    double var = lq[0] * (1.0 / 131072.0) - mu * mu;
    double aj  = (double)g[j] / sqrt(var + 1e-5);
    a[j] = aj;
    c[j] = (double)be[j] - mu * aj;
  }
}

// ---------------- host side ----------------
extern "C" void kernel_launch(void* const* d_in, const int* in_sizes, int n_in,
                              void* d_out, int out_size, void* d_ws, size_t ws_size,
                              hipStream_t stream)
{
  const float* F[23];
  for (int i = 0; i < 23; ++i) F[i] = (const float*)d_in[i];
  const float* ev = F[0];
  float* out0 = (float*)d_out;
  float* out1 = out0 + BATCH * 64;

  // partials live in d_out (consumed before the final pass overwrites it)
  double* partials = (double*)d_out;
  double* bn_a = (double*)d_ws;          // 450 doubles
  double* bn_c = bn_a + 450;             // 450 doubles
  unsigned* maps = (unsigned*)(bn_c + 450);  // 64 u32

  char* ws = (char*)d_ws;
  size_t used = (size_t)((char*)(maps + 64) - ws);
  used = (used + 255) & ~(size_t)255;
  const size_t needA = (size_t)BATCH * 130 * 8;   // 136.3 MB
  const size_t needB = (size_t)BATCH * 110 * 8;   // 115.3 MB

  dim3 b(256);

  if (ws_size >= used + needA + needB) {
    // ---------- fast stored-h path (f64 MFMA, probe-measured layout) ----------
    double* bufA = (double*)(ws + used);
    double* bufB = (double*)(ws + used + needA);
    dim3 g(GBLOCKS);
    probe_layout<<<dim3(1), dim3(64), 0, stream>>>(maps);
    gemm_mfma<1024, 130, 0><<<g, b, 0, stream>>>(ev, F[1], F[2],
        nullptr, nullptr, maps, bufA, partials);
    bn_finalize2<130><<<dim3(130), b, 0, stream>>>(partials, GBLOCKS, F[3], F[4], bn_a + 0, bn_c + 0);
    gemm_mfma<130, 110, 1><<<g, b, 0, stream>>>(bufA, F[5], F[6],
        bn_a + 0, bn_c + 0, maps, bufB, partials);
    bn_finalize2<110><<<dim3(110), b, 0, stream>>>(partials, GBLOCKS, F[7], F[8], bn_a + 130, bn_c + 130);
    gemm_mfma<110, 90, 1><<<g, b, 0, stream>>>(bufB, F[9], F[10],
        bn_a + 130, bn_c + 130, maps, bufA, partials);
    bn_finalize2<90><<<dim3(90), b, 0, stream>>>(partials, GBLOCKS, F[11], F[12], bn_a + 240, bn_c + 240);
    gemm_mfma<90, 70, 1><<<g, b, 0, stream>>>(bufA, F[13], F[14],
        bn_a + 240, bn_c + 240, maps, bufB, partials);
    bn_finalize2<70><<<dim3(70), b, 0, stream>>>(partials, GBLOCKS, F[15], F[16], bn_a + 330, bn_c + 330);
    gemm_mfma<70, 50, 1><<<g, b, 0, stream>>>(bufB, F[17], F[18],
        bn_a + 330, bn_c + 330, maps, bufA, partials);
    bn_finalize2<50><<<dim3(50), b, 0, stream>>>(partials, GBLOCKS, F[19], F[20], bn_a + 400, bn_c + 400);
    final_store<<<dim3(NBLOCKS), b, 0, stream>>>(bufA, bn_a + 400, bn_c + 400, F[21], F[22], out0, out1);
  } else {
    // ---------- fallback: verified recompute chain ----------
    dim3 g(NBLOCKS);
#define ARGS ev, F[1],F[2], F[5],F[6], F[9],F[10], F[13],F[14], F[17],F[18], \
             F[21],F[22], bn_a, bn_c, partials, out0, out1
    chain_pass<0><<<g, b, 0, stream>>>(ARGS);
    bn_finalize2<130><<<dim3(130), b, 0, stream>>>(partials, NBLOCKS, F[3],  F[4],  bn_a + 0,   bn_c + 0);
    chain_pass<1><<<g, b, 0, stream>>>(ARGS);
    bn_finalize2<110><<<dim3(110), b, 0, stream>>>(partials, NBLOCKS, F[7],  F[8],  bn_a + 130, bn_c + 130);
    chain_pass<2><<<g, b, 0, stream>>>(ARGS);
    bn_finalize2<90><<<dim3(90),  b, 0, stream>>>(partials, NBLOCKS, F[11], F[12], bn_a + 240, bn_c + 240);
    chain_pass<3><<<g, b, 0, stream>>>(ARGS);
    bn_finalize2<70><<<dim3(70),  b, 0, stream>>>(partials, NBLOCKS, F[15], F[16], bn_a + 330, bn_c + 330);
    chain_pass<4><<<g, b, 0, stream>>>(ARGS);
    bn_finalize2<50><<<dim3(50),  b, 0, stream>>>(partials, NBLOCKS, F[19], F[20], bn_a + 400, bn_c + 400);
    chain_pass<5><<<g, b, 0, stream>>>(ARGS);
#undef ARGS
  }
}

// Round 15
// 1086.671 us; speedup vs baseline: 1.0205x; 1.0205x over previous
//
#include <hip/hip_runtime.h>
#include <type_traits>

// ---------------- problem constants ----------------
static const long BATCH = 131072;
static const int ROWS = 32;                  // rows per block (final/fallback)
static const int NBLOCKS = 4096;             // fallback/final grid
static const int GBLOCKS = 2048;             // gemm_mfma grid (64 rows each)

using f64x4 = __attribute__((ext_vector_type(4))) double;

// ---------------- threefry2x32 (JAX partitionable, key = (0, 42)) ----------
__device__ __forceinline__ unsigned rotl32(unsigned x, int d) {
  return (x << d) | (x >> (32 - d));
}

struct U2 { unsigned a, b; };

__device__ __forceinline__ U2 threefry(unsigned x0, unsigned x1) {
  const unsigned ks0 = 0u, ks1 = 42u, ks2 = 0u ^ 42u ^ 0x1BD11BDAu;
  x0 += ks0; x1 += ks1;
#define TF_R4(A,B,C,D) \
  x0 += x1; x1 = rotl32(x1, A); x1 ^= x0; \
  x0 += x1; x1 = rotl32(x1, B); x1 ^= x0; \
  x0 += x1; x1 = rotl32(x1, C); x1 ^= x0; \
  x0 += x1; x1 = rotl32(x1, D); x1 ^= x0;
  TF_R4(13,15,26,6)  x0 += ks1; x1 += ks2 + 1u;
  TF_R4(17,29,16,24) x0 += ks2; x1 += ks0 + 2u;
  TF_R4(13,15,26,6)  x0 += ks0; x1 += ks1 + 3u;
  TF_R4(17,29,16,24) x0 += ks1; x1 += ks2 + 4u;
  TF_R4(13,15,26,6)  x0 += ks2; x1 += ks0 + 5u;
#undef TF_R4
  U2 r; r.a = x0; r.b = x1; return r;
}

// partitionable 32-bit draw: bits1 ^ bits2  (VERIFIED passing, round 4)
__device__ __forceinline__ float jax_uniform(unsigned idx) {
  U2 r = threefry(0u, idx);
  unsigned bits = r.a ^ r.b;
  unsigned fb = (bits >> 9) | 0x3f800000u;
  return __uint_as_float(fb) - 1.0f;
}

// ============ f64-MFMA D-fragment layout probe (VERIFIED round 7) ==========
__global__ __launch_bounds__(64) void probe_layout(unsigned* __restrict__ maps) {
  __shared__ double X1[16][5], X2[16][5], W1s[4][17], W2s[4][17];
  const int l = threadIdx.x;
  const int lr = l & 15, lk = l >> 4;
  {
    int i = l >> 2, k = l & 3;
    X1[i][k] = (k == 0) ? (double)i : 0.0;   // D1[i][j] = i
    X2[i][k] = (k == 0) ? 1.0 : 0.0;         // D2[i][j] = j
    W1s[k][i] = (k == 0) ? 1.0 : 0.0;
    W2s[k][i] = (k == 0) ? (double)i : 0.0;
  }
  __syncthreads();
  f64x4 a1 = {0.0, 0.0, 0.0, 0.0}, a2 = {0.0, 0.0, 0.0, 0.0};
  a1 = __builtin_amdgcn_mfma_f64_16x16x4f64(X1[lr][lk], W1s[lk][lr], a1, 0, 0, 0);
  a2 = __builtin_amdgcn_mfma_f64_16x16x4f64(X2[lr][lk], W2s[lk][lr], a2, 0, 0, 0);
  unsigned m = 0;
  #pragma unroll
  for (int r = 0; r < 4; ++r) {
    int row = (int)(a1[r] + 0.5);
    int col = (int)(a2[r] + 0.5);
    m |= (unsigned)(((row & 15) << 4) | (col & 15)) << (8 * r);
  }
  maps[l] = m;
}

// ====== FAST PATH: f64-MFMA GEMM (R9 K-loop + barrier-light epilogue) ======
// h[B][N] = act(in[B][M]) @ W[N][M]^T + b; col stats partials transposed.
// K-loop: R9 verbatim (best measured). Epilogue: runtime-checks the probe
// map; if D layout == (row=lr, col=4*lk+r) -> DIRECT reg->global stores
// (2x double2/lane/tile, no LDS, no barriers) + shfl-tree column stats
// (1 barrier total). Otherwise -> R9's map-driven tt epilogue (safe).
template<int M, int N, int MODE>
__global__ __launch_bounds__(256, 3) void gemm_mfma(
    const void* __restrict__ inv, const float* __restrict__ W,
    const float* __restrict__ bias,
    const double* __restrict__ bna, const double* __restrict__ bnc,
    const unsigned* __restrict__ maps_g,
    double* __restrict__ hout, double* __restrict__ partials)
{
  constexpr int BK = 16;
  constexpr int NT = (N + 15) / 16;
  constexpr int NPAD = NT * 16;
  constexpr int WSTR = NPAD + 2;              // lk-groups 8 banks apart
  constexpr int NCH = (M + BK - 1) / BK;
  constexpr int NW = BK * NPAD;
  constexpr int WLD = (NW + 255) / 256;
  constexpr int SMK = (MODE == 1) ? (NCH * BK) : 1;

  struct SMW { float ws[2][BK][WSTR]; };
  union SMU {
    SMW m;
    double tt[4][16][17];                     // SAFE epilogue transpose tile
    double ss[4][2][NPAD];                    // FAST epilogue wave stats
  };
  __shared__ SMU sm;
  __shared__ double bnsm[2][SMK];

  const int tid = threadIdx.x;
  const int w = tid >> 6, l = tid & 63;
  const int lr = l & 15, lk = l >> 4;
  const long i0 = (long)blockIdx.x * 64;
  const int wrow = w * 16;
  const unsigned um = maps_g[l];
  const long arow = i0 + wrow + lr;           // this lane's A row

  if constexpr (MODE == 1) {
    for (int k = tid; k < SMK; k += 256) {
      bnsm[0][k] = (k < M) ? bna[k] : 0.0;
      bnsm[1][k] = (k < M) ? bnc[k] : 0.0;
    }
  }

  float wreg[WLD];
  float a4f[4], a4fn[4];
  double a4d[4], a4dn[4];

  auto loadW = [&](int k0) {
    #pragma unroll
    for (int p = 0; p < WLD; ++p) {
      int idx = tid + p * 256;
      float v = 0.0f;
      if (idx < NW) {
        int j = idx >> 4, kk = idx & 15;
        int k = k0 + kk;
        if (j < N && k < M) v = W[(long)j * M + k];
      }
      wreg[p] = v;
    }
  };
  auto writeW = [&](int buf) {
    #pragma unroll
    for (int p = 0; p < WLD; ++p) {
      int idx = tid + p * 256;
      if (idx < NW) {
        int j = idx >> 4, kk = idx & 15;
        sm.m.ws[buf][kk][j] = wreg[p];
      }
    }
  };
  auto loadA = [&](int k0, bool nxt) {
    int kb = k0 + lk * 4;
    if constexpr (MODE == 0) {
      float* dst = nxt ? a4fn : a4f;
      float4 v = *(const float4*)((const float*)inv + arow * (long)M + kb);
      dst[0] = v.x; dst[1] = v.y; dst[2] = v.z; dst[3] = v.w;
    } else {
      double* dst = nxt ? a4dn : a4d;
      if (kb + 4 <= M) {
        const double* ap = (const double*)inv + arow * (long)M + kb;
        double2 lo = *(const double2*)ap;
        double2 hi = *(const double2*)(ap + 2);
        dst[0] = lo.x; dst[1] = lo.y; dst[2] = hi.x; dst[3] = hi.y;
      } else {
        #pragma unroll
        for (int e = 0; e < 4; ++e)
          dst[e] = (kb + e < M) ? ((const double*)inv)[arow * (long)M + kb + e] : 0.0;
      }
    }
  };

  f64x4 acc[NT];
  #pragma unroll
  for (int t = 0; t < NT; ++t) acc[t] = (f64x4){0.0, 0.0, 0.0, 0.0};

  loadA(0, false);
  loadW(0);
  writeW(0);
  __syncthreads();
  int cur = 0;
  for (int ch = 0; ch < NCH; ++ch) {
    const int k0 = ch * BK;
    if (ch + 1 < NCH) { loadA(k0 + BK, true); loadW(k0 + BK); }
    #pragma unroll
    for (int ks = 0; ks < 4; ++ks) {
      double aA;
      if constexpr (MODE == 0) {
        aA = (double)a4f[ks];
      } else {
        int k = k0 + lk * 4 + ks;
        double v = a4d[ks] * bnsm[0][k] + bnsm[1][k];
        aA = v > 0.0 ? v : 0.0;
      }
      #pragma unroll
      for (int t = 0; t < NT; ++t) {
        double bB = (double)sm.m.ws[cur][lk * 4 + ks][t * 16 + lr];
        acc[t] = __builtin_amdgcn_mfma_f64_16x16x4f64(aA, bB, acc[t], 0, 0, 0);
      }
    }
    if (ch + 1 < NCH) writeW(cur ^ 1);
    __syncthreads();                          // last iter: frees sm union
    if (ch + 1 < NCH) {
      if constexpr (MODE == 0) {
        #pragma unroll
        for (int e = 0; e < 4; ++e) a4f[e] = a4fn[e];
      } else {
        #pragma unroll
        for (int e = 0; e < 4; ++e) a4d[e] = a4dn[e];
      }
      cur ^= 1;
    }
  }

  const int blk = blockIdx.x;

  // ---- epilogue selection: does D follow (row=lr, col=4*lk+r)? ----
  unsigned expect = 0;
  #pragma unroll
  for (int r = 0; r < 4; ++r)
    expect |= (unsigned)((lr << 4) | ((lk * 4 + r) & 15)) << (8 * r);

  if (__all(um == expect)) {
    // ================= FAST epilogue: no LDS for h, 1 barrier ==============
    const long row = i0 + wrow + lr;
    #pragma unroll
    for (int t = 0; t < NT; ++t) {
      const int colbase = t * 16 + lk * 4;
      double hv[4], s[4], q[4];
      #pragma unroll
      for (int r = 0; r < 4; ++r) {
        int j = colbase + r;
        bool ok = (j < N);
        double h = acc[t][r] + (ok ? (double)bias[j] : 0.0);
        hv[r] = h;
        s[r] = ok ? h : 0.0;
        q[r] = ok ? h * h : 0.0;
      }
      // direct stores: lane's 4 regs = 4 consecutive cols of one row
      if (colbase + 3 < N) {                  // 16B-aligned (N even, colbase%4==0)
        double* hp = hout + row * (long)N + colbase;
        *(double2*)hp       = make_double2(hv[0], hv[1]);
        *(double2*)(hp + 2) = make_double2(hv[2], hv[3]);
      } else {
        #pragma unroll
        for (int r = 0; r < 4; ++r)
          if (colbase + r < N) hout[row * (long)N + colbase + r] = hv[r];
      }
      // column stats: reduce over the 16 rows (lanes lr=0..15 in this lk group)
      #pragma unroll
      for (int r = 0; r < 4; ++r) {
        #pragma unroll
        for (int off = 1; off < 16; off <<= 1) {
          s[r] += __shfl_xor(s[r], off);
          q[r] += __shfl_xor(q[r], off);
        }
      }
      if (lr == 0) {
        #pragma unroll
        for (int r = 0; r < 4; ++r) {
          sm.ss[w][0][colbase + r] = s[r];
          sm.ss[w][1][colbase + r] = q[r];
        }
      }
    }
    __syncthreads();
    for (int j = tid; j < N; j += 256) {
      double s4 = sm.ss[0][0][j] + sm.ss[1][0][j] + sm.ss[2][0][j] + sm.ss[3][0][j];
      double q4 = sm.ss[0][1][j] + sm.ss[1][1][j] + sm.ss[2][1][j] + sm.ss[3][1][j];
      partials[(long)j * GBLOCKS + blk] = s4;
      partials[(long)(N + j) * GBLOCKS + blk] = q4;
    }
  } else {
    // ================= SAFE epilogue: R9 map-driven tt path ================
    for (int t = 0; t < NT; ++t) {
      __syncthreads();
      #pragma unroll
      for (int r = 0; r < 4; ++r) {
        unsigned b = (um >> (8 * r)) & 0xffu;
        sm.tt[w][b >> 4][b & 15] = acc[t][r];
      }
      __syncthreads();
      for (int idx = tid; idx < 1024; idx += 256) {
        int rb = idx >> 4, j16 = idx & 15;
        int j = t * 16 + j16;
        if (j < N) {
          double h = sm.tt[rb >> 4][rb & 15][j16] + (double)bias[j];
          hout[(i0 + rb) * (long)N + j] = h;
        }
      }
      if (tid < 64) {
        int j16 = tid >> 2, part = tid & 3;
        int j = t * 16 + j16;
        double s = 0.0, q = 0.0;
        if (j < N) {
          double bj = (double)bias[j];
          #pragma unroll
          for (int rr = 0; rr < 16; ++rr) {
            int rb = part * 16 + rr;
            double h = sm.tt[rb >> 4][rb & 15][j16] + bj;
            s += h; q += h * h;
          }
        }
        s += __shfl_xor(s, 1); s += __shfl_xor(s, 2);
        q += __shfl_xor(q, 1); q += __shfl_xor(q, 2);
        if (part == 0 && j < N) {
          partials[(long)j * GBLOCKS + blk] = s;
          partials[(long)(N + j) * GBLOCKS + blk] = q;
        }
      }
    }
  }
}

// final: BN+ReLU(h4) -> Linear(50->64) -> sigmoid -> sample -> logsum
__global__ __launch_bounds__(256) void final_store(
    const double* __restrict__ h4,
    const double* __restrict__ bna, const double* __restrict__ bnc,
    const float* __restrict__ W5, const float* __restrict__ b5,
    float* __restrict__ out0, float* __restrict__ out1)
{
  __shared__ double A5[ROWS][51];
  __shared__ double W5S[50][65];
  __shared__ double T[ROWS][65];
  const int tid = threadIdx.x;
  const int c = tid & 63, g = tid >> 6;
  const long i0 = (long)blockIdx.x * ROWS;

  for (int idx = tid; idx < ROWS * 50; idx += 256) {
    int r = idx / 50, k = idx % 50;
    double v = h4[(i0 + r) * 50 + k] * bna[k] + bnc[k];
    A5[r][k] = v > 0.0 ? v : 0.0;
  }
  for (int idx = tid; idx < 64 * 50; idx += 256) {
    int j = idx / 50, k = idx % 50;
    W5S[k][j] = (double)W5[j * 50 + k];
  }
  __syncthreads();

  double acc[8];
  #pragma unroll
  for (int rr = 0; rr < 8; ++rr) acc[rr] = 0.0;
  for (int k = 0; k < 50; ++k) {
    double w = W5S[k][c];
    #pragma unroll
    for (int rr = 0; rr < 8; ++rr) acc[rr] += A5[g * 8 + rr][k] * w;
  }
  double bj = (double)b5[c];
  #pragma unroll
  for (int rr = 0; rr < 8; ++rr) {
    int r = g * 8 + rr;
    double h = acc[rr] + bj;
    double p = 1.0 / (1.0 + exp(-h));
    float uf = jax_uniform((unsigned)((i0 + r) * 64 + c));
    bool ch = ((double)uf < 1.0 - p);
    out0[(i0 + r) * 64 + c] = ch ? 0.0f : 1.0f;
    T[r][c] = log(ch ? (1.0 - p) : p);
  }
  __syncthreads();
  for (int r = tid; r < ROWS; r += 256) {
    double s = 0.0;
    for (int j = 0; j < 64; ++j) s += T[r][j];
    out1[i0 + r] = (float)s;
  }
}

// ======================= FALLBACK: recompute chain (verified) ==============
template<int M, int N>
__device__ __forceinline__ void step_gemm(const double* IN, const float* __restrict__ W,
                                          int tid, double* acc) {
  if (tid < N) {
    #pragma unroll
    for (int r = 0; r < 32; ++r) acc[r] = 0.0;
    for (int k = 0; k < M; ++k) {
      double wv = (double)W[tid * M + k];
      #pragma unroll
      for (int r = 0; r < 32; ++r) acc[r] += IN[r * M + k] * wv;
    }
  }
}

template<int N>
__device__ __forceinline__ void step_write(double* OUT, const double* acc,
                                           const float* __restrict__ b, int tid) {
  if (tid < N) {
    double bj = (double)b[tid];
    #pragma unroll
    for (int r = 0; r < 32; ++r) OUT[r * N + tid] = acc[r] + bj;
  }
}

// transposed partials layout: partials[j*NBLOCKS + blk]
template<int N>
__device__ __forceinline__ void step_stats(const double* acc, const float* __restrict__ b,
                                           double* partials, int blk, int tid) {
  if (tid < N) {
    double bj = (double)b[tid], s = 0.0, q = 0.0;
    #pragma unroll
    for (int r = 0; r < 32; ++r) { double h = acc[r] + bj; s += h; q += h * h; }
    partials[(long)tid * NBLOCKS + blk] = s;
    partials[(long)(N + tid) * NBLOCKS + blk] = q;
  }
}

template<int N>
__device__ __forceinline__ void apply_bn(double* BUF, const double* __restrict__ a,
                                         const double* __restrict__ c, int tid) {
  for (int idx = tid; idx < 32 * N; idx += 256) {
    int col = idx % N;
    double v = BUF[idx] * a[col] + c[col];
    BUF[idx] = v > 0.0 ? v : 0.0;
  }
}

template<int PL>
__global__ __launch_bounds__(256) void chain_pass(
    const float* __restrict__ ev,
    const float* __restrict__ W0, const float* __restrict__ b0,
    const float* __restrict__ W1, const float* __restrict__ b1,
    const float* __restrict__ W2, const float* __restrict__ b2,
    const float* __restrict__ W3, const float* __restrict__ b3,
    const float* __restrict__ W4, const float* __restrict__ b4,
    const float* __restrict__ W5, const float* __restrict__ b5,
    const double* __restrict__ bn_a, const double* __restrict__ bn_c,
    double* __restrict__ partials,
    float* __restrict__ out0, float* __restrict__ out1)
{
  __shared__ double SA[32 * 130];
  __shared__ double SB[32 * 110];
  const int tid = threadIdx.x;
  const int blk = blockIdx.x;
  const long i0 = (long)blk * 32;
  double acc[32];

  {
    float* evf = (float*)SA;
    if (tid < 130) {
      #pragma unroll
      for (int r = 0; r < 32; ++r) acc[r] = 0.0;
    }
    for (int c = 0; c < 4; ++c) {
      __syncthreads();
      for (int idx = tid; idx < 32 * 256; idx += 256) {
        int r = idx >> 8, kk = idx & 255;
        evf[idx] = ev[(i0 + r) * 1024 + c * 256 + kk];
      }
      __syncthreads();
      if (tid < 130) {
        for (int kk = 0; kk < 256; ++kk) {
          double wv = (double)W0[tid * 1024 + c * 256 + kk];
          #pragma unroll
          for (int r = 0; r < 32; ++r) acc[r] += (double)evf[r * 256 + kk] * wv;
        }
      }
    }
    __syncthreads();
    if constexpr (PL == 0) { step_stats<130>(acc, b0, partials, blk, tid); return; }
    step_write<130>(SA, acc, b0, tid);
    __syncthreads();
    apply_bn<130>(SA, bn_a + 0, bn_c + 0, tid);
    __syncthreads();
  }
  if constexpr (PL >= 1) {
    step_gemm<130, 110>(SA, W1, tid, acc);
    if constexpr (PL == 1) { step_stats<110>(acc, b1, partials, blk, tid); return; }
    __syncthreads();
    step_write<110>(SB, acc, b1, tid);
    __syncthreads();
    apply_bn<110>(SB, bn_a + 130, bn_c + 130, tid);
    __syncthreads();
  }
  if constexpr (PL >= 2) {
    step_gemm<110, 90>(SB, W2, tid, acc);
    if constexpr (PL == 2) { step_stats<90>(acc, b2, partials, blk, tid); return; }
    __syncthreads();
    step_write<90>(SA, acc, b2, tid);
    __syncthreads();
    apply_bn<90>(SA, bn_a + 240, bn_c + 240, tid);
    __syncthreads();
  }
  if constexpr (PL >= 3) {
    step_gemm<90, 70>(SA, W3, tid, acc);
    if constexpr (PL == 3) { step_stats<70>(acc, b3, partials, blk, tid); return; }
    __syncthreads();
    step_write<70>(SB, acc, b3, tid);
    __syncthreads();
    apply_bn<70>(SB, bn_a + 330, bn_c + 330, tid);
    __syncthreads();
  }
  if constexpr (PL >= 4) {
    step_gemm<70, 50>(SB, W4, tid, acc);
    if constexpr (PL == 4) { step_stats<50>(acc, b4, partials, blk, tid); return; }
    __syncthreads();
    step_write<50>(SA, acc, b4, tid);
    __syncthreads();
    apply_bn<50>(SA, bn_a + 400, bn_c + 400, tid);
    __syncthreads();
  }
  if constexpr (PL == 5) {
    if (tid < 64) {
      #pragma unroll
      for (int r = 0; r < 32; ++r) acc[r] = 0.0;
      for (int k = 0; k < 50; ++k) {
        double wv = (double)W5[tid * 50 + k];
        #pragma unroll
        for (int r = 0; r < 32; ++r) acc[r] += SA[r * 50 + k] * wv;
      }
      double bj = (double)b5[tid];
      #pragma unroll
      for (int r = 0; r < 32; ++r) {
        double h = acc[r] + bj;
        double p = 1.0 / (1.0 + exp(-h));
        float uf = jax_uniform((unsigned)((i0 + r) * 64 + tid));
        bool ch = ((double)uf < 1.0 - p);
        out0[(i0 + r) * 64 + tid] = ch ? 0.0f : 1.0f;
        double d = ch ? (1.0 - p) : p;
        SB[r * 64 + tid] = log(d);
      }
    }
    __syncthreads();
    if (tid < 32) {
      double s = 0.0;
      for (int j = 0; j < 64; ++j) s += SB[tid * 64 + j];
      out1[i0 + tid] = (float)s;
    }
  }
}

// ------- BN stats finalize: transposed partials -> a, c (coalesced) --------
template<int N>
__global__ __launch_bounds__(256) void bn_finalize2(
    const double* __restrict__ partials, int nblocks,
    const float* __restrict__ g, const float* __restrict__ be,
    double* __restrict__ a, double* __restrict__ c)
{
  const int j = blockIdx.x;
  const int tid = threadIdx.x;
  double s = 0.0, q = 0.0;
  for (int b = tid; b < nblocks; b += 256) {
    s += partials[(long)j * nblocks + b];
    q += partials[(long)(N + j) * nblocks + b];
  }
  __shared__ double ls[256], lq[256];
  ls[tid] = s; lq[tid] = q;
  __syncthreads();
  for (int off = 128; off > 0; off >>= 1) {
    if (tid < off) { ls[tid] += ls[tid + off]; lq[tid] += lq[tid + off]; }
    __syncthreads();
  }
  if (tid == 0) {
    double mu  = ls[0] * (1.0 / 131072.0);
    double var = lq[0] * (1.0 / 131072.0) - mu * mu;
    double aj  = (double)g[j] / sqrt(var + 1e-5);
    a[j] = aj;
    c[j] = (double)be[j] - mu * aj;
  }
}

// ---------------- host side ----------------
extern "C" void kernel_launch(void* const* d_in, const int* in_sizes, int n_in,
                              void* d_out, int out_size, void* d_ws, size_t ws_size,
                              hipStream_t stream)
{
  const float* F[23];
  for (int i = 0; i < 23; ++i) F[i] = (const float*)d_in[i];
  const float* ev = F[0];
  float* out0 = (float*)d_out;
  float* out1 = out0 + BATCH * 64;

  // partials live in d_out (consumed before the final pass overwrites it)
  double* partials = (double*)d_out;
  double* bn_a = (double*)d_ws;          // 450 doubles
  double* bn_c = bn_a + 450;             // 450 doubles
  unsigned* maps = (unsigned*)(bn_c + 450);  // 64 u32

  char* ws = (char*)d_ws;
  size_t used = (size_t)((char*)(maps + 64) - ws);
  used = (used + 255) & ~(size_t)255;
  const size_t needA = (size_t)BATCH * 130 * 8;   // 136.3 MB
  const size_t needB = (size_t)BATCH * 110 * 8;   // 115.3 MB

  dim3 b(256);

  if (ws_size >= used + needA + needB) {
    // ---------- fast stored-h path (f64 MFMA, probe-measured layout) ----------
    double* bufA = (double*)(ws + used);
    double* bufB = (double*)(ws + used + needA);
    dim3 g(GBLOCKS);
    probe_layout<<<dim3(1), dim3(64), 0, stream>>>(maps);
    gemm_mfma<1024, 130, 0><<<g, b, 0, stream>>>(ev, F[1], F[2],
        nullptr, nullptr, maps, bufA, partials);
    bn_finalize2<130><<<dim3(130), b, 0, stream>>>(partials, GBLOCKS, F[3], F[4], bn_a + 0, bn_c + 0);
    gemm_mfma<130, 110, 1><<<g, b, 0, stream>>>(bufA, F[5], F[6],
        bn_a + 0, bn_c + 0, maps, bufB, partials);
    bn_finalize2<110><<<dim3(110), b, 0, stream>>>(partials, GBLOCKS, F[7], F[8], bn_a + 130, bn_c + 130);
    gemm_mfma<110, 90, 1><<<g, b, 0, stream>>>(bufB, F[9], F[10],
        bn_a + 130, bn_c + 130, maps, bufA, partials);
    bn_finalize2<90><<<dim3(90), b, 0, stream>>>(partials, GBLOCKS, F[11], F[12], bn_a + 240, bn_c + 240);
    gemm_mfma<90, 70, 1><<<g, b, 0, stream>>>(bufA, F[13], F[14],
        bn_a + 240, bn_c + 240, maps, bufB, partials);
    bn_finalize2<70><<<dim3(70), b, 0, stream>>>(partials, GBLOCKS, F[15], F[16], bn_a + 330, bn_c + 330);
    gemm_mfma<70, 50, 1><<<g, b, 0, stream>>>(bufB, F[17], F[18],
        bn_a + 330, bn_c + 330, maps, bufA, partials);
    bn_finalize2<50><<<dim3(50), b, 0, stream>>>(partials, GBLOCKS, F[19], F[20], bn_a + 400, bn_c + 400);
    final_store<<<dim3(NBLOCKS), b, 0, stream>>>(bufA, bn_a + 400, bn_c + 400, F[21], F[22], out0, out1);
  } else {
    // ---------- fallback: verified recompute chain ----------
    dim3 g(NBLOCKS);
#define ARGS ev, F[1],F[2], F[5],F[6], F[9],F[10], F[13],F[14], F[17],F[18], \
             F[21],F[22], bn_a, bn_c, partials, out0, out1
    chain_pass<0><<<g, b, 0, stream>>>(ARGS);
    bn_finalize2<130><<<dim3(130), b, 0, stream>>>(partials, NBLOCKS, F[3],  F[4],  bn_a + 0,   bn_c + 0);
    chain_pass<1><<<g, b, 0, stream>>>(ARGS);
    bn_finalize2<110><<<dim3(110), b, 0, stream>>>(partials, NBLOCKS, F[7],  F[8],  bn_a + 130, bn_c + 130);
    chain_pass<2><<<g, b, 0, stream>>>(ARGS);
    bn_finalize2<90><<<dim3(90),  b, 0, stream>>>(partials, NBLOCKS, F[11], F[12], bn_a + 240, bn_c + 240);
    chain_pass<3><<<g, b, 0, stream>>>(ARGS);
    bn_finalize2<70><<<dim3(70),  b, 0, stream>>>(partials, NBLOCKS, F[15], F[16], bn_a + 330, bn_c + 330);
    chain_pass<4><<<g, b, 0, stream>>>(ARGS);
    bn_finalize2<50><<<dim3(50),  b, 0, stream>>>(partials, NBLOCKS, F[19], F[20], bn_a + 400, bn_c + 400);
    chain_pass<5><<<g, b, 0, stream>>>(ARGS);
#undef ARGS
  }
}

// Round 17
// 1039.991 us; speedup vs baseline: 1.0663x; 1.0449x over previous
//
#include <hip/hip_runtime.h>
#include <type_traits>

// ---------------- problem constants ----------------
static const long BATCH = 131072;
static const int ROWS = 32;                  // rows per block (final/fallback)
static const int NBLOCKS = 4096;             // fallback/final grid
static const int GBLOCKS = 2048;             // gemm_mfma grid (64 rows each)

using f64x4 = __attribute__((ext_vector_type(4))) double;

// ---------------- threefry2x32 (JAX partitionable, key = (0, 42)) ----------
__device__ __forceinline__ unsigned rotl32(unsigned x, int d) {
  return (x << d) | (x >> (32 - d));
}

struct U2 { unsigned a, b; };

__device__ __forceinline__ U2 threefry(unsigned x0, unsigned x1) {
  const unsigned ks0 = 0u, ks1 = 42u, ks2 = 0u ^ 42u ^ 0x1BD11BDAu;
  x0 += ks0; x1 += ks1;
#define TF_R4(A,B,C,D) \
  x0 += x1; x1 = rotl32(x1, A); x1 ^= x0; \
  x0 += x1; x1 = rotl32(x1, B); x1 ^= x0; \
  x0 += x1; x1 = rotl32(x1, C); x1 ^= x0; \
  x0 += x1; x1 = rotl32(x1, D); x1 ^= x0;
  TF_R4(13,15,26,6)  x0 += ks1; x1 += ks2 + 1u;
  TF_R4(17,29,16,24) x0 += ks2; x1 += ks0 + 2u;
  TF_R4(13,15,26,6)  x0 += ks0; x1 += ks1 + 3u;
  TF_R4(17,29,16,24) x0 += ks1; x1 += ks2 + 4u;
  TF_R4(13,15,26,6)  x0 += ks2; x1 += ks0 + 5u;
#undef TF_R4
  U2 r; r.a = x0; r.b = x1; return r;
}

// partitionable 32-bit draw: bits1 ^ bits2  (VERIFIED passing, round 4)
__device__ __forceinline__ float jax_uniform(unsigned idx) {
  U2 r = threefry(0u, idx);
  unsigned bits = r.a ^ r.b;
  unsigned fb = (bits >> 9) | 0x3f800000u;
  return __uint_as_float(fb) - 1.0f;
}

// ============ f64-MFMA D-fragment layout probe (VERIFIED round 7) ==========
__global__ __launch_bounds__(64) void probe_layout(unsigned* __restrict__ maps) {
  __shared__ double X1[16][5], X2[16][5], W1s[4][17], W2s[4][17];
  const int l = threadIdx.x;
  const int lr = l & 15, lk = l >> 4;
  {
    int i = l >> 2, k = l & 3;
    X1[i][k] = (k == 0) ? (double)i : 0.0;   // D1[i][j] = i
    X2[i][k] = (k == 0) ? 1.0 : 0.0;         // D2[i][j] = j
    W1s[k][i] = (k == 0) ? 1.0 : 0.0;
    W2s[k][i] = (k == 0) ? (double)i : 0.0;
  }
  __syncthreads();
  f64x4 a1 = {0.0, 0.0, 0.0, 0.0}, a2 = {0.0, 0.0, 0.0, 0.0};
  a1 = __builtin_amdgcn_mfma_f64_16x16x4f64(X1[lr][lk], W1s[lk][lr], a1, 0, 0, 0);
  a2 = __builtin_amdgcn_mfma_f64_16x16x4f64(X2[lr][lk], W2s[lk][lr], a2, 0, 0, 0);
  unsigned m = 0;
  #pragma unroll
  for (int r = 0; r < 4; ++r) {
    int row = (int)(a1[r] + 0.5);
    int col = (int)(a2[r] + 0.5);
    m |= (unsigned)(((row & 15) << 4) | (col & 15)) << (8 * r);
  }
  maps[l] = m;
}

// ====== FAST PATH: f64-MFMA GEMM (R9 loop; NREM VALU remainder cols) =======
// h[B][N] = act(in[B][M]) @ W[N][M]^T + b; col stats partials transposed.
// MFMA covers NT = (N-NREM)/16 tiles; last NREM (<4) cols on the idle VALU.
// FIX vs R16: stage NSTG = max(NPAD, N) columns ZERO-PADDED for j >= N and
// restore j<N guards in the tt epilogue (MODE-1 layers have NPAD > N; R16
// read unstaged LDS and stored past the row end -> absmax 44).
template<int M, int N, int MODE, int NREM>
__global__ __launch_bounds__(256, 3) void gemm_mfma(
    const void* __restrict__ inv, const float* __restrict__ W,
    const float* __restrict__ bias,
    const double* __restrict__ bna, const double* __restrict__ bnc,
    const unsigned* __restrict__ maps_g,
    double* __restrict__ hout, double* __restrict__ partials)
{
  constexpr int BK = 16;
  constexpr int NT = (N - NREM + 15) / 16;    // MFMA tiles
  constexpr int NPAD = NT * 16;               // MFMA-covered cols
  constexpr int NSTG = (NPAD > N) ? NPAD : N; // staged cols (zero-padded)
  constexpr int WSTR = NSTG + 2;              // staged row stride (f32)
  constexpr int NCH = (M + BK - 1) / BK;
  constexpr int NW = BK * NSTG;
  constexpr int WLD = (NW + 255) / 256;
  constexpr int SMK = (MODE == 1) ? (NCH * BK) : 1;

  struct SMW { float ws[2][BK][WSTR]; };
  union SMU {
    SMW m;
    double tt[4][16][17];                     // epilogue transpose tile
  };
  __shared__ SMU sm;
  __shared__ double bnsm[2][SMK];
  __shared__ double rem_s[4][2][NREM > 0 ? NREM : 1];

  const int tid = threadIdx.x;
  const int w = tid >> 6, l = tid & 63;
  const int lr = l & 15, lk = l >> 4;
  const long i0 = (long)blockIdx.x * 64;
  const int wrow = w * 16;
  const unsigned um = maps_g[l];
  const long arow = i0 + wrow + lr;           // this lane's A row

  if constexpr (MODE == 1) {
    for (int k = tid; k < SMK; k += 256) {
      bnsm[0][k] = (k < M) ? bna[k] : 0.0;
      bnsm[1][k] = (k < M) ? bnc[k] : 0.0;
    }
  }

  float wreg[WLD];
  float a4f[4], a4fn[4];
  double a4d[4], a4dn[4];

  auto loadW = [&](int k0) {
    #pragma unroll
    for (int p = 0; p < WLD; ++p) {
      int idx = tid + p * 256;
      float v = 0.0f;
      if (idx < NW) {
        int j = idx >> 4, kk = idx & 15;
        int k = k0 + kk;
        if (j < N && k < M) v = W[(long)j * M + k];   // zero-pad j >= N
      }
      wreg[p] = v;
    }
  };
  auto writeW = [&](int buf) {
    #pragma unroll
    for (int p = 0; p < WLD; ++p) {
      int idx = tid + p * 256;
      if (idx < NW) {
        int j = idx >> 4, kk = idx & 15;
        sm.m.ws[buf][kk][j] = wreg[p];
      }
    }
  };
  auto loadA = [&](int k0, bool nxt) {
    int kb = k0 + lk * 4;
    if constexpr (MODE == 0) {
      float* dst = nxt ? a4fn : a4f;
      float4 v = *(const float4*)((const float*)inv + arow * (long)M + kb);
      dst[0] = v.x; dst[1] = v.y; dst[2] = v.z; dst[3] = v.w;
    } else {
      double* dst = nxt ? a4dn : a4d;
      if (kb + 4 <= M) {
        const double* ap = (const double*)inv + arow * (long)M + kb;
        double2 lo = *(const double2*)ap;
        double2 hi = *(const double2*)(ap + 2);
        dst[0] = lo.x; dst[1] = lo.y; dst[2] = hi.x; dst[3] = hi.y;
      } else {
        #pragma unroll
        for (int e = 0; e < 4; ++e)
          dst[e] = (kb + e < M) ? ((const double*)inv)[arow * (long)M + kb + e] : 0.0;
      }
    }
  };

  f64x4 acc[NT];
  #pragma unroll
  for (int t = 0; t < NT; ++t) acc[t] = (f64x4){0.0, 0.0, 0.0, 0.0};
  double racc[NREM > 0 ? NREM : 1];
  #pragma unroll
  for (int c = 0; c < (NREM > 0 ? NREM : 1); ++c) racc[c] = 0.0;

  loadA(0, false);
  loadW(0);
  writeW(0);
  __syncthreads();
  int cur = 0;
  for (int ch = 0; ch < NCH; ++ch) {
    const int k0 = ch * BK;
    if (ch + 1 < NCH) { loadA(k0 + BK, true); loadW(k0 + BK); }
    #pragma unroll
    for (int ks = 0; ks < 4; ++ks) {
      double aA;
      if constexpr (MODE == 0) {
        aA = (double)a4f[ks];
      } else {
        int k = k0 + lk * 4 + ks;
        double v = a4d[ks] * bnsm[0][k] + bnsm[1][k];
        aA = v > 0.0 ? v : 0.0;
      }
      #pragma unroll
      for (int t = 0; t < NT; ++t) {
        double bB = (double)sm.m.ws[cur][lk * 4 + ks][t * 16 + lr];
        acc[t] = __builtin_amdgcn_mfma_f64_16x16x4f64(aA, bB, acc[t], 0, 0, 0);
      }
      if constexpr (NREM == 2) {
        // one b64 broadcast read covers both remainder cols (8B-aligned)
        float2 rv = *(const float2*)&sm.m.ws[cur][lk * 4 + ks][NPAD];
        racc[0] += aA * (double)rv.x;
        racc[1] += aA * (double)rv.y;
      } else if constexpr (NREM > 0) {
        #pragma unroll
        for (int c = 0; c < NREM; ++c)
          racc[c] += aA * (double)sm.m.ws[cur][lk * 4 + ks][NPAD + c];
      }
    }
    if (ch + 1 < NCH) writeW(cur ^ 1);
    __syncthreads();
    if (ch + 1 < NCH) {
      if constexpr (MODE == 0) {
        #pragma unroll
        for (int e = 0; e < 4; ++e) a4f[e] = a4fn[e];
      } else {
        #pragma unroll
        for (int e = 0; e < 4; ++e) a4d[e] = a4dn[e];
      }
      cur ^= 1;
    }
  }

  const int blk = blockIdx.x;

  // ---- remainder columns: butterfly k-reduce, store h, column stats ----
  if constexpr (NREM > 0) {
    #pragma unroll
    for (int c = 0; c < NREM; ++c) {
      racc[c] += __shfl_xor(racc[c], 16);     // sum over lk groups
      racc[c] += __shfl_xor(racc[c], 32);
      int j = NPAD + c;
      double h = racc[c] + (double)bias[j];
      if (lk == 0) hout[(i0 + wrow + lr) * (long)N + j] = h;
      double s = h, q = h * h;
      #pragma unroll
      for (int off = 1; off < 16; off <<= 1) { // sum over 16 rows (lr)
        s += __shfl_xor(s, off);
        q += __shfl_xor(q, off);
      }
      if (l == 0) { rem_s[w][0][c] = s; rem_s[w][1][c] = q; }
    }
  }
  __syncthreads();
  if constexpr (NREM > 0) {
    if (tid < NREM) {
      int j = NPAD + tid;
      partials[(long)j * GBLOCKS + blk] =
          rem_s[0][0][tid] + rem_s[1][0][tid] + rem_s[2][0][tid] + rem_s[3][0][tid];
      partials[(long)(N + j) * GBLOCKS + blk] =
          rem_s[0][1][tid] + rem_s[1][1][tid] + rem_s[2][1][tid] + rem_s[3][1][tid];
    }
  }

  // ---- epilogue: map-driven LDS transpose (tt unions staging), store+stats --
  for (int t = 0; t < NT; ++t) {
    __syncthreads();
    #pragma unroll
    for (int r = 0; r < 4; ++r) {
      unsigned b = (um >> (8 * r)) & 0xffu;
      sm.tt[w][b >> 4][b & 15] = acc[t][r];
    }
    __syncthreads();
    for (int idx = tid; idx < 1024; idx += 256) {
      int rb = idx >> 4, j16 = idx & 15;
      int j = t * 16 + j16;
      if (j < N) {
        double h = sm.tt[rb >> 4][rb & 15][j16] + (double)bias[j];
        hout[(i0 + rb) * (long)N + j] = h;
      }
    }
    if (tid < 64) {
      int j16 = tid >> 2, part = tid & 3;
      int j = t * 16 + j16;
      double s = 0.0, q = 0.0;
      if (j < N) {
        double bj = (double)bias[j];
        #pragma unroll
        for (int rr = 0; rr < 16; ++rr) {
          int rb = part * 16 + rr;
          double h = sm.tt[rb >> 4][rb & 15][j16] + bj;
          s += h; q += h * h;
        }
      }
      s += __shfl_xor(s, 1); s += __shfl_xor(s, 2);
      q += __shfl_xor(q, 1); q += __shfl_xor(q, 2);
      if (part == 0 && j < N) {
        partials[(long)j * GBLOCKS + blk] = s;
        partials[(long)(N + j) * GBLOCKS + blk] = q;
      }
    }
  }
}

// final: BN+ReLU(h4) -> Linear(50->64) -> sigmoid -> sample -> logsum
__global__ __launch_bounds__(256) void final_store(
    const double* __restrict__ h4,
    const double* __restrict__ bna, const double* __restrict__ bnc,
    const float* __restrict__ W5, const float* __restrict__ b5,
    float* __restrict__ out0, float* __restrict__ out1)
{
  __shared__ double A5[ROWS][51];
  __shared__ double W5S[50][65];
  __shared__ double T[ROWS][65];
  const int tid = threadIdx.x;
  const int c = tid & 63, g = tid >> 6;
  const long i0 = (long)blockIdx.x * ROWS;

  for (int idx = tid; idx < ROWS * 50; idx += 256) {
    int r = idx / 50, k = idx % 50;
    double v = h4[(i0 + r) * 50 + k] * bna[k] + bnc[k];
    A5[r][k] = v > 0.0 ? v : 0.0;
  }
  for (int idx = tid; idx < 64 * 50; idx += 256) {
    int j = idx / 50, k = idx % 50;
    W5S[k][j] = (double)W5[j * 50 + k];
  }
  __syncthreads();

  double acc[8];
  #pragma unroll
  for (int rr = 0; rr < 8; ++rr) acc[rr] = 0.0;
  for (int k = 0; k < 50; ++k) {
    double w = W5S[k][c];
    #pragma unroll
    for (int rr = 0; rr < 8; ++rr) acc[rr] += A5[g * 8 + rr][k] * w;
  }
  double bj = (double)b5[c];
  #pragma unroll
  for (int rr = 0; rr < 8; ++rr) {
    int r = g * 8 + rr;
    double h = acc[rr] + bj;
    double p = 1.0 / (1.0 + exp(-h));
    float uf = jax_uniform((unsigned)((i0 + r) * 64 + c));
    bool ch = ((double)uf < 1.0 - p);
    out0[(i0 + r) * 64 + c] = ch ? 0.0f : 1.0f;
    T[r][c] = log(ch ? (1.0 - p) : p);
  }
  __syncthreads();
  for (int r = tid; r < ROWS; r += 256) {
    double s = 0.0;
    for (int j = 0; j < 64; ++j) s += T[r][j];
    out1[i0 + r] = (float)s;
  }
}

// ======================= FALLBACK: recompute chain (verified) ==============
template<int M, int N>
__device__ __forceinline__ void step_gemm(const double* IN, const float* __restrict__ W,
                                          int tid, double* acc) {
  if (tid < N) {
    #pragma unroll
    for (int r = 0; r < 32; ++r) acc[r] = 0.0;
    for (int k = 0; k < M; ++k) {
      double wv = (double)W[tid * M + k];
      #pragma unroll
      for (int r = 0; r < 32; ++r) acc[r] += IN[r * M + k] * wv;
    }
  }
}

template<int N>
__device__ __forceinline__ void step_write(double* OUT, const double* acc,
                                           const float* __restrict__ b, int tid) {
  if (tid < N) {
    double bj = (double)b[tid];
    #pragma unroll
    for (int r = 0; r < 32; ++r) OUT[r * N + tid] = acc[r] + bj;
  }
}

// transposed partials layout: partials[j*NBLOCKS + blk]
template<int N>
__device__ __forceinline__ void step_stats(const double* acc, const float* __restrict__ b,
                                           double* partials, int blk, int tid) {
  if (tid < N) {
    double bj = (double)b[tid], s = 0.0, q = 0.0;
    #pragma unroll
    for (int r = 0; r < 32; ++r) { double h = acc[r] + bj; s += h; q += h * h; }
    partials[(long)tid * NBLOCKS + blk] = s;
    partials[(long)(N + tid) * NBLOCKS + blk] = q;
  }
}

template<int N>
__device__ __forceinline__ void apply_bn(double* BUF, const double* __restrict__ a,
                                         const double* __restrict__ c, int tid) {
  for (int idx = tid; idx < 32 * N; idx += 256) {
    int col = idx % N;
    double v = BUF[idx] * a[col] + c[col];
    BUF[idx] = v > 0.0 ? v : 0.0;
  }
}

template<int PL>
__global__ __launch_bounds__(256) void chain_pass(
    const float* __restrict__ ev,
    const float* __restrict__ W0, const float* __restrict__ b0,
    const float* __restrict__ W1, const float* __restrict__ b1,
    const float* __restrict__ W2, const float* __restrict__ b2,
    const float* __restrict__ W3, const float* __restrict__ b3,
    const float* __restrict__ W4, const float* __restrict__ b4,
    const float* __restrict__ W5, const float* __restrict__ b5,
    const double* __restrict__ bn_a, const double* __restrict__ bn_c,
    double* __restrict__ partials,
    float* __restrict__ out0, float* __restrict__ out1)
{
  __shared__ double SA[32 * 130];
  __shared__ double SB[32 * 110];
  const int tid = threadIdx.x;
  const int blk = blockIdx.x;
  const long i0 = (long)blk * 32;
  double acc[32];

  {
    float* evf = (float*)SA;
    if (tid < 130) {
      #pragma unroll
      for (int r = 0; r < 32; ++r) acc[r] = 0.0;
    }
    for (int c = 0; c < 4; ++c) {
      __syncthreads();
      for (int idx = tid; idx < 32 * 256; idx += 256) {
        int r = idx >> 8, kk = idx & 255;
        evf[idx] = ev[(i0 + r) * 1024 + c * 256 + kk];
      }
      __syncthreads();
      if (tid < 130) {
        for (int kk = 0; kk < 256; ++kk) {
          double wv = (double)W0[tid * 1024 + c * 256 + kk];
          #pragma unroll
          for (int r = 0; r < 32; ++r) acc[r] += (double)evf[r * 256 + kk] * wv;
        }
      }
    }
    __syncthreads();
    if constexpr (PL == 0) { step_stats<130>(acc, b0, partials, blk, tid); return; }
    step_write<130>(SA, acc, b0, tid);
    __syncthreads();
    apply_bn<130>(SA, bn_a + 0, bn_c + 0, tid);
    __syncthreads();
  }
  if constexpr (PL >= 1) {
    step_gemm<130, 110>(SA, W1, tid, acc);
    if constexpr (PL == 1) { step_stats<110>(acc, b1, partials, blk, tid); return; }
    __syncthreads();
    step_write<110>(SB, acc, b1, tid);
    __syncthreads();
    apply_bn<110>(SB, bn_a + 130, bn_c + 130, tid);
    __syncthreads();
  }
  if constexpr (PL >= 2) {
    step_gemm<110, 90>(SB, W2, tid, acc);
    if constexpr (PL == 2) { step_stats<90>(acc, b2, partials, blk, tid); return; }
    __syncthreads();
    step_write<90>(SA, acc, b2, tid);
    __syncthreads();
    apply_bn<90>(SA, bn_a + 240, bn_c + 240, tid);
    __syncthreads();
  }
  if constexpr (PL >= 3) {
    step_gemm<90, 70>(SA, W3, tid, acc);
    if constexpr (PL == 3) { step_stats<70>(acc, b3, partials, blk, tid); return; }
    __syncthreads();
    step_write<70>(SB, acc, b3, tid);
    __syncthreads();
    apply_bn<70>(SB, bn_a + 330, bn_c + 330, tid);
    __syncthreads();
  }
  if constexpr (PL >= 4) {
    step_gemm<70, 50>(SB, W4, tid, acc);
    if constexpr (PL == 4) { step_stats<50>(acc, b4, partials, blk, tid); return; }
    __syncthreads();
    step_write<50>(SA, acc, b4, tid);
    __syncthreads();
    apply_bn<50>(SA, bn_a + 400, bn_c + 400, tid);
    __syncthreads();
  }
  if constexpr (PL == 5) {
    if (tid < 64) {
      #pragma unroll
      for (int r = 0; r < 32; ++r) acc[r] = 0.0;
      for (int k = 0; k < 50; ++k) {
        double wv = (double)W5[tid * 50 + k];
        #pragma unroll
        for (int r = 0; r < 32; ++r) acc[r] += SA[r * 50 + k] * wv;
      }
      double bj = (double)b5[tid];
      #pragma unroll
      for (int r = 0; r < 32; ++r) {
        double h = acc[r] + bj;
        double p = 1.0 / (1.0 + exp(-h));
        float uf = jax_uniform((unsigned)((i0 + r) * 64 + tid));
        bool ch = ((double)uf < 1.0 - p);
        out0[(i0 + r) * 64 + tid] = ch ? 0.0f : 1.0f;
        double d = ch ? (1.0 - p) : p;
        SB[r * 64 + tid] = log(d);
      }
    }
    __syncthreads();
    if (tid < 32) {
      double s = 0.0;
      for (int j = 0; j < 64; ++j) s += SB[tid * 64 + j];
      out1[i0 + tid] = (float)s;
    }
  }
}

// ------- BN stats finalize: transposed partials -> a, c (coalesced) --------
template<int N>
__global__ __launch_bounds__(256) void bn_finalize2(
    const double* __restrict__ partials, int nblocks,
    const float* __restrict__ g, const float* __restrict__ be,
    double* __restrict__ a, double* __restrict__ c)
{
  const int j = blockIdx.x;
  const int tid = threadIdx.x;
  double s = 0.0, q = 0.0;
  for (int b = tid; b < nblocks; b += 256) {
    s += partials[(long)j * nblocks + b];
    q += partials[(long)(N + j) * nblocks + b];
  }
  __shared__ double ls[256], lq[256];
  ls[tid] = s; lq[tid] = q;
  __syncthreads();
  for (int off = 128; off > 0; off >>= 1) {
    if (tid < off) { ls[tid] += ls[tid + off]; lq[tid] += lq[tid + off]; }
    __syncthreads();
  }
  if (tid == 0) {
    double mu  = ls[0] * (1.0 / 131072.0);
    double var = lq[0] * (1.0 / 131072.0) - mu * mu;
    double aj  = (double)g[j] / sqrt(var + 1e-5);
    a[j] = aj;
    c[j] = (double)be[j] - mu * aj;
  }
}

// ---------------- host side ----------------
extern "C" void kernel_launch(void* const* d_in, const int* in_sizes, int n_in,
                              void* d_out, int out_size, void* d_ws, size_t ws_size,
                              hipStream_t stream)
{
  const float* F[23];
  for (int i = 0; i < 23; ++i) F[i] = (const float*)d_in[i];
  const float* ev = F[0];
  float* out0 = (float*)d_out;
  float* out1 = out0 + BATCH * 64;

  // partials live in d_out (consumed before the final pass overwrites it)
  double* partials = (double*)d_out;
  double* bn_a = (double*)d_ws;          // 450 doubles
  double* bn_c = bn_a + 450;             // 450 doubles
  unsigned* maps = (unsigned*)(bn_c + 450);  // 64 u32

  char* ws = (char*)d_ws;
  size_t used = (size_t)((char*)(maps + 64) - ws);
  used = (used + 255) & ~(size_t)255;
  const size_t needA = (size_t)BATCH * 130 * 8;   // 136.3 MB
  const size_t needB = (size_t)BATCH * 110 * 8;   // 115.3 MB

  dim3 b(256);

  if (ws_size >= used + needA + needB) {
    // ---------- fast stored-h path (f64 MFMA, probe-measured layout) ----------
    double* bufA = (double*)(ws + used);
    double* bufB = (double*)(ws + used + needA);
    dim3 g(GBLOCKS);
    probe_layout<<<dim3(1), dim3(64), 0, stream>>>(maps);
    gemm_mfma<1024, 130, 0, 2><<<g, b, 0, stream>>>(ev, F[1], F[2],
        nullptr, nullptr, maps, bufA, partials);
    bn_finalize2<130><<<dim3(130), b, 0, stream>>>(partials, GBLOCKS, F[3], F[4], bn_a + 0, bn_c + 0);
    gemm_mfma<130, 110, 1, 0><<<g, b, 0, stream>>>(bufA, F[5], F[6],
        bn_a + 0, bn_c + 0, maps, bufB, partials);
    bn_finalize2<110><<<dim3(110), b, 0, stream>>>(partials, GBLOCKS, F[7], F[8], bn_a + 130, bn_c + 130);
    gemm_mfma<110, 90, 1, 0><<<g, b, 0, stream>>>(bufB, F[9], F[10],
        bn_a + 130, bn_c + 130, maps, bufA, partials);
    bn_finalize2<90><<<dim3(90), b, 0, stream>>>(partials, GBLOCKS, F[11], F[12], bn_a + 240, bn_c + 240);
    gemm_mfma<90, 70, 1, 0><<<g, b, 0, stream>>>(bufA, F[13], F[14],
        bn_a + 240, bn_c + 240, maps, bufB, partials);
    bn_finalize2<70><<<dim3(70), b, 0, stream>>>(partials, GBLOCKS, F[15], F[16], bn_a + 330, bn_c + 330);
    gemm_mfma<70, 50, 1, 0><<<g, b, 0, stream>>>(bufB, F[17], F[18],
        bn_a + 330, bn_c + 330, maps, bufA, partials);
    bn_finalize2<50><<<dim3(50), b, 0, stream>>>(partials, GBLOCKS, F[19], F[20], bn_a + 400, bn_c + 400);
    final_store<<<dim3(NBLOCKS), b, 0, stream>>>(bufA, bn_a + 400, bn_c + 400, F[21], F[22], out0, out1);
  } else {
    // ---------- fallback: verified recompute chain ----------
    dim3 g(NBLOCKS);
#define ARGS ev, F[1],F[2], F[5],F[6], F[9],F[10], F[13],F[14], F[17],F[18], \
             F[21],F[22], bn_a, bn_c, partials, out0, out1
    chain_pass<0><<<g, b, 0, stream>>>(ARGS);
    bn_finalize2<130><<<dim3(130), b, 0, stream>>>(partials, NBLOCKS, F[3],  F[4],  bn_a + 0,   bn_c + 0);
    chain_pass<1><<<g, b, 0, stream>>>(ARGS);
    bn_finalize2<110><<<dim3(110), b, 0, stream>>>(partials, NBLOCKS, F[7],  F[8],  bn_a + 130, bn_c + 130);
    chain_pass<2><<<g, b, 0, stream>>>(ARGS);
    bn_finalize2<90><<<dim3(90),  b, 0, stream>>>(partials, NBLOCKS, F[11], F[12], bn_a + 240, bn_c + 240);
    chain_pass<3><<<g, b, 0, stream>>>(ARGS);
    bn_finalize2<70><<<dim3(70),  b, 0, stream>>>(partials, NBLOCKS, F[15], F[16], bn_a + 330, bn_c + 330);
    chain_pass<4><<<g, b, 0, stream>>>(ARGS);
    bn_finalize2<50><<<dim3(50),  b, 0, stream>>>(partials, NBLOCKS, F[19], F[20], bn_a + 400, bn_c + 400);
    chain_pass<5><<<g, b, 0, stream>>>(ARGS);
#undef ARGS
  }
}